// Round 11
// baseline (185.475 us; speedup 1.0000x reference)
//
#include <hip/hip_runtime.h>
#include <math.h>

// LinearAttention: out[n,l,h,m] = (phi(Q[l])·KV[:,m]) / (phi(Q[l])·Ksum + eps)
//   KV[d][m] = sum_s phi(K[s,d]) V[s,m],  Ksum[d] = sum_s phi(K[s,d])
//   phi(x) = elu(x)+1 = x>0 ? x+1 : exp(x)

#define N_B 8
#define S_LEN 8192
#define H_N 8
#define D_DIM 64
#define NH (N_B * H_N)
#define EPS 1e-6f
#define ROWSTRIDE (H_N * D_DIM)   // 512 floats between consecutive s rows
#define NCHUNK 32
#define CROWS (S_LEN / NCHUNK)    // 256 s-rows per block
#define RROWS 64                  // s-rows per round (one burst)
#define ROUNDS (CROWS / RROWS)    // 4

typedef __attribute__((ext_vector_type(8)))  __bf16 bf16x8;
typedef __attribute__((ext_vector_type(4)))  float  f32x4;
typedef __attribute__((ext_vector_type(4)))  int    i32x4;
typedef __attribute__((ext_vector_type(2)))  int    i32x2;

__device__ __forceinline__ float felu1(float x) {
    return x > 0.0f ? x + 1.0f : __expf(x);
}
__device__ __forceinline__ unsigned bfb(float f) {
    __bf16 h = (__bf16)f;                       // RNE convert
    return (unsigned)__builtin_bit_cast(unsigned short, h);
}
__device__ __forceinline__ int pack2bf(float a, float b) {
    return (int)(bfb(a) | (bfb(b) << 16));
}

// ---------------- Phase 1a: one-burst-per-round MFMA KV partial -------------
// out_kernel's proven memory shape: per round each thread issues 8 dwordx4
// loads in ONE burst (thread = one s-row x 16 d), converts in-register,
// 4x ds_write_b128, ONE raw s_barrier (lgkmcnt only -- loads for the next
// round stay in flight across it; no vmcnt(0) drain, T4). Compute: R9's
// verified tr_b16 subtile layout + mfma_f32_16x16x32_bf16; wave w owns d-rows
// 16w..16w+15; Ksum via MFMA with B=ones. 2048 blocks, 32 KB LDS dbuf.
__global__ __launch_bounds__(256) void kv_partial_kernel(
        const float* __restrict__ Kin, const float* __restrict__ Vin,
        float* __restrict__ kvp,   // [NH*NCHUNK][64*64]
        float* __restrict__ ksp) { // [NH*NCHUNK][64]
    __shared__ __align__(16) __bf16 KT[2][4096];  // 8 KB per buffer
    __shared__ __align__(16) __bf16 VT[2][4096];

    const int b    = blockIdx.x;
    const int h_i  = b & 7;
    const int rest = b >> 3;
    const int c    = rest & (NCHUNK - 1);
    const int n_i  = rest >> 5;                 // NCHUNK = 32
    const int ob   = (n_i * H_N + h_i) * NCHUNK + c;
    const int s0   = c * CROWS;

    const int t = threadIdx.x;
    const int w = t >> 6;        // wave 0..3 -> d-block w
    const int l = t & 63;

    const float* Kb = Kin + (size_t)n_i * S_LEN * ROWSTRIDE + (size_t)h_i * D_DIM;
    const float* Vb = Vin + (size_t)n_i * S_LEN * ROWSTRIDE + (size_t)h_i * D_DIM;

    // staging role: thread = (s-row srow, d-block dq of 16 cols)
    const int srow = t & 63;
    const int dq   = t >> 6;

    float4 kr[4], vr[4];         // one in-flight burst: 8 dwordx4 = 128 B

    auto issue = [&](int round) {
        const float* kp = Kb + (size_t)(s0 + round * RROWS + srow) * ROWSTRIDE + dq * 16;
        const float* vp = Vb + (size_t)(s0 + round * RROWS + srow) * ROWSTRIDE + dq * 16;
        #pragma unroll
        for (int i = 0; i < 4; ++i) kr[i] = ((const float4*)kp)[i];
        #pragma unroll
        for (int i = 0; i < 4; ++i) vr[i] = ((const float4*)vp)[i];
    };

    // LDS line layout: d-block dq (2048 B) / s-line s>>2 (128 B) /
    // slot (s&3)^((s>>2)&3) (32 B, XOR-swizzled) / 16 bf16 d-values
    const int wbyte = dq * 2048 + (srow >> 2) * 128
                    + (((srow & 3) ^ ((srow >> 2) & 3)) * 32);

    auto convwrite = [&](int buf) {
        int kp8[8], vp8[8];
        #pragma unroll
        for (int i = 0; i < 4; ++i) {
            kp8[2 * i]     = pack2bf(felu1(kr[i].x), felu1(kr[i].y));
            kp8[2 * i + 1] = pack2bf(felu1(kr[i].z), felu1(kr[i].w));
            vp8[2 * i]     = pack2bf(vr[i].x, vr[i].y);
            vp8[2 * i + 1] = pack2bf(vr[i].z, vr[i].w);
        }
        char* kb = (char*)&KT[buf][0] + wbyte;
        char* vb = (char*)&VT[buf][0] + wbyte;
        *(i32x4*)kb        = (i32x4){kp8[0], kp8[1], kp8[2], kp8[3]};
        *(i32x4*)(kb + 16) = (i32x4){kp8[4], kp8[5], kp8[6], kp8[7]};
        *(i32x4*)vb        = (i32x4){vp8[0], vp8[1], vp8[2], vp8[3]};
        *(i32x4*)(vb + 16) = (i32x4){vp8[4], vp8[5], vp8[6], vp8[7]};
    };

    f32x4 acc[4];
    f32x4 ksacc = (f32x4){0.f, 0.f, 0.f, 0.f};
    #pragma unroll
    for (int i = 0; i < 4; ++i) acc[i] = (f32x4){0.f, 0.f, 0.f, 0.f};
    const bf16x8 ONES = __builtin_bit_cast(bf16x8,
        (i32x4){0x3F803F80, 0x3F803F80, 0x3F803F80, 0x3F803F80});

    // tr-read: group g=l>>4 reads lines 2g,2g+1 (s=8g..8g+7); lane l&15 = d col
    const int rdlane = (l & 15) * 8 + (l >> 4) * 256;

    auto compute = [&](int buf) {
        unsigned kbase, vbase;
        {
            auto k3 = (__attribute__((address_space(3))) char*)&KT[buf][0];
            auto v3 = (__attribute__((address_space(3))) char*)&VT[buf][0];
            kbase = (unsigned)(size_t)k3 + rdlane;
            vbase = (unsigned)(size_t)v3 + rdlane;
        }
        bf16x8 A[2];
        {
            const unsigned ka = kbase + w * 2048;
            i32x2 r0, r1, r2, r3;
            asm volatile("ds_read_b64_tr_b16 %0, %4\n\t"
                         "ds_read_b64_tr_b16 %1, %4 offset:128\n\t"
                         "ds_read_b64_tr_b16 %2, %4 offset:1024\n\t"
                         "ds_read_b64_tr_b16 %3, %4 offset:1152"
                         : "=&v"(r0), "=&v"(r1), "=&v"(r2), "=&v"(r3) : "v"(ka));
            asm volatile("s_waitcnt lgkmcnt(0)" ::: "memory");
            __builtin_amdgcn_sched_barrier(0);
            A[0] = __builtin_bit_cast(bf16x8, (i32x4){r0.x, r0.y, r1.x, r1.y});
            A[1] = __builtin_bit_cast(bf16x8, (i32x4){r2.x, r2.y, r3.x, r3.y});
        }
        ksacc = __builtin_amdgcn_mfma_f32_16x16x32_bf16(A[0], ONES, ksacc, 0, 0, 0);
        ksacc = __builtin_amdgcn_mfma_f32_16x16x32_bf16(A[1], ONES, ksacc, 0, 0, 0);
        #pragma unroll
        for (int mt = 0; mt < 4; ++mt) {
            const unsigned va = vbase + mt * 2048;
            i32x2 b0, b1, b2, b3;
            asm volatile("ds_read_b64_tr_b16 %0, %4\n\t"
                         "ds_read_b64_tr_b16 %1, %4 offset:128\n\t"
                         "ds_read_b64_tr_b16 %2, %4 offset:1024\n\t"
                         "ds_read_b64_tr_b16 %3, %4 offset:1152"
                         : "=&v"(b0), "=&v"(b1), "=&v"(b2), "=&v"(b3) : "v"(va));
            asm volatile("s_waitcnt lgkmcnt(0)" ::: "memory");
            __builtin_amdgcn_sched_barrier(0);
            const bf16x8 B0 = __builtin_bit_cast(bf16x8, (i32x4){b0.x, b0.y, b1.x, b1.y});
            const bf16x8 B1 = __builtin_bit_cast(bf16x8, (i32x4){b2.x, b2.y, b3.x, b3.y});
            acc[mt] = __builtin_amdgcn_mfma_f32_16x16x32_bf16(A[0], B0, acc[mt], 0, 0, 0);
            acc[mt] = __builtin_amdgcn_mfma_f32_16x16x32_bf16(A[1], B1, acc[mt], 0, 0, 0);
        }
    };

    // prologue: burst 0, convert+write buf0, prefetch burst 1, barrier
    issue(0);
    convwrite(0);
    issue(1);
    asm volatile("s_waitcnt lgkmcnt(0)" ::: "memory");
    __builtin_amdgcn_s_barrier();

    for (int r = 0; r < ROUNDS; ++r) {
        compute(r & 1);                       // loads for r+1 fly over this
        if (r + 1 < ROUNDS) {
            convwrite((r + 1) & 1);           // vmcnt wait lands here only
            if (r + 2 < ROUNDS) issue(r + 2); // next burst out before barrier
        }
        asm volatile("s_waitcnt lgkmcnt(0)" ::: "memory");
        __builtin_amdgcn_s_barrier();         // raw: no vmcnt drain (T4)
    }

    // ---- write partial KV: D col = l&15, row = (l>>4)*4 + reg ----
    float* kvo = kvp + (size_t)ob * (D_DIM * D_DIM);
    #pragma unroll
    for (int mt = 0; mt < 4; ++mt) {
        #pragma unroll
        for (int r = 0; r < 4; ++r) {
            const int row = 16 * w + (l >> 4) * 4 + r;   // d
            const int col = 16 * mt + (l & 15);          // m
            kvo[row * 64 + col] = acc[mt][r];
        }
    }
    if ((l & 15) == 0) {
        #pragma unroll
        for (int r = 0; r < 4; ++r)
            ksp[(size_t)ob * D_DIM + 16 * w + (l >> 4) * 4 + r] = ksacc[r];
    }
}

// ---------------- Phase 1b: reduce partials -> final KV, Ksum ----------------
__global__ __launch_bounds__(256) void kv_reduce_kernel(
        const float* __restrict__ kvp, const float* __restrict__ ksp,
        float* __restrict__ KV, float* __restrict__ Ksum) {
    const int nh = blockIdx.x >> 4;
    const int eb = blockIdx.x & 15;
    const int t  = threadIdx.x;
    const int e  = eb * 256 + t;
    float s = 0.0f;
    const float* base = kvp + (size_t)nh * NCHUNK * (D_DIM * D_DIM) + e;
    #pragma unroll 8
    for (int c = 0; c < NCHUNK; ++c)
        s += base[(size_t)c * (D_DIM * D_DIM)];
    KV[(size_t)nh * (D_DIM * D_DIM) + e] = s;
    if (eb == 0 && t < D_DIM) {
        float ks = 0.0f;
        #pragma unroll 8
        for (int c = 0; c < NCHUNK; ++c)
            ks += ksp[(size_t)nh * NCHUNK * D_DIM + (size_t)c * D_DIM + t];
        Ksum[(size_t)nh * D_DIM + t] = ks;
    }
}

// ---------------- Phase 2: out = (Q·KV) / (Q·Ksum + eps) ----------------
// Grid remap: b = ((n*nblk + rb) * 8) + h (R8, kept -- 6.2 TB/s measured).
__global__ __launch_bounds__(256) void out_kernel(
        const float* __restrict__ Qin, const float* __restrict__ KV,
        const float* __restrict__ Ksum, float* __restrict__ Out) {
    constexpr int RPB  = 128;
    constexpr int QPAD = 68;
    __shared__ __align__(16) float KVs[D_DIM][D_DIM];   // 16 KB
    __shared__ __align__(16) float Kss[D_DIM];
    __shared__ __align__(16) float Qs[RPB][QPAD];       // 34.8 KB, XOR-swizzled cols

    const int b    = blockIdx.x;
    const int nblk = S_LEN / RPB;          // 64
    const int h_i  = b & 7;
    const int rest = b >> 3;
    const int rb   = rest & (nblk - 1);
    const int n_i  = rest >> 6;            // nblk = 64
    const int nh   = n_i * H_N + h_i;
    const int t    = threadIdx.x;

    const float* Qb = Qin + (size_t)n_i * S_LEN * ROWSTRIDE + (size_t)h_i * D_DIM;
    float*       Ob = Out + (size_t)n_i * S_LEN * ROWSTRIDE + (size_t)h_i * D_DIM;

    {
        const float4* src = (const float4*)(KV + (size_t)nh * (D_DIM * D_DIM));
        float4* dst = (float4*)(&KVs[0][0]);
        #pragma unroll
        for (int i = 0; i < 4; ++i) dst[t + 256 * i] = src[t + 256 * i];
        if (t < 16) ((float4*)Kss)[t] = ((const float4*)(Ksum + (size_t)nh * D_DIM))[t];
    }

    const int ltx = t & 15, lty = t >> 4;
    const int sbase = rb * RPB;
    #pragma unroll
    for (int i = 0; i < 8; ++i) {
        const int row = lty + 16 * i;
        const float4 q = *(const float4*)(Qb + (size_t)(sbase + row) * ROWSTRIDE + ltx * 4);
        float4 f;
        f.x = felu1(q.x); f.y = felu1(q.y); f.z = felu1(q.z); f.w = felu1(q.w);
        const int pc = (ltx * 4) ^ (((row >> 2) & 7) << 2);
        *(float4*)&Qs[row][pc] = f;
    }
    __syncthreads();

    const int rg = t >> 3;                 // 0..31 -> rows rg*4..rg*4+3
    const int mg = t & 7;                  // 0..7  -> cols mg*8..mg*8+7
    const int r0 = rg * 4, m0 = mg * 8;
    const int sw = ((rg & 7) << 2);

    float acc[4][8];
    float zz[4];
    #pragma unroll
    for (int r = 0; r < 4; ++r) {
        zz[r] = 0.0f;
        #pragma unroll
        for (int m = 0; m < 8; ++m) acc[r][m] = 0.0f;
    }

    #pragma unroll
    for (int d0 = 0; d0 < D_DIM; d0 += 4) {
        const float4 ks4 = *(const float4*)&Kss[d0];
        float4 qr[4];
        #pragma unroll
        for (int r = 0; r < 4; ++r) {
            qr[r] = *(const float4*)&Qs[r0 + r][d0 ^ sw];
            zz[r] += qr[r].x * ks4.x + qr[r].y * ks4.y
                   + qr[r].z * ks4.z + qr[r].w * ks4.w;
        }
        #pragma unroll
        for (int j = 0; j < 4; ++j) {
            const float4 kva = *(const float4*)&KVs[d0 + j][m0];
            const float4 kvb = *(const float4*)&KVs[d0 + j][m0 + 4];
            #pragma unroll
            for (int r = 0; r < 4; ++r) {
                const float q = (&qr[r].x)[j];
                acc[r][0] += q * kva.x; acc[r][1] += q * kva.y;
                acc[r][2] += q * kva.z; acc[r][3] += q * kva.w;
                acc[r][4] += q * kvb.x; acc[r][5] += q * kvb.y;
                acc[r][6] += q * kvb.z; acc[r][7] += q * kvb.w;
            }
        }
    }

    #pragma unroll
    for (int r = 0; r < 4; ++r) {
        const float z = 1.0f / (zz[r] + EPS);
        float4 o1, o2;
        o1.x = acc[r][0] * z; o1.y = acc[r][1] * z;
        o1.z = acc[r][2] * z; o1.w = acc[r][3] * z;
        o2.x = acc[r][4] * z; o2.y = acc[r][5] * z;
        o2.z = acc[r][6] * z; o2.w = acc[r][7] * z;
        float* op = Ob + (size_t)(sbase + r0 + r) * ROWSTRIDE + m0;
        *(float4*)op       = o1;
        *(float4*)(op + 4) = o2;
    }
}

extern "C" void kernel_launch(void* const* d_in, const int* in_sizes, int n_in,
                              void* d_out, int out_size, void* d_ws, size_t ws_size,
                              hipStream_t stream) {
    const float* q = (const float*)d_in[0];
    const float* k = (const float*)d_in[1];
    const float* v = (const float*)d_in[2];
    float* out = (float*)d_out;

    float* kvp  = (float*)d_ws;                                   // 33.6 MB
    float* ksp  = kvp + (size_t)NH * NCHUNK * D_DIM * D_DIM;      // 0.5 MB
    float* KVf  = ksp + (size_t)NH * NCHUNK * D_DIM;              // 1.05 MB
    float* Ksum = KVf + (size_t)NH * D_DIM * D_DIM;

    kv_partial_kernel<<<N_B * NCHUNK * H_N, 256, 0, stream>>>(k, v, kvp, ksp);
    kv_reduce_kernel<<<NH * 16, 256, 0, stream>>>(kvp, ksp, KVf, Ksum);
    out_kernel<<<NH * (S_LEN / 128), 256, 0, stream>>>(q, KVf, Ksum, out);
}

// Round 12
// 169.221 us; speedup vs baseline: 1.0961x; 1.0961x over previous
//
#include <hip/hip_runtime.h>
#include <math.h>

// LinearAttention: out[n,l,h,m] = (phi(Q[l])·KV[:,m]) / (phi(Q[l])·Ksum + eps)
//   KV[d][m] = sum_s phi(K[s,d]) V[s,m],  Ksum[d] = sum_s phi(K[s,d])
//   phi(x) = elu(x)+1 = x>0 ? x+1 : exp(x)

#define N_B 8
#define S_LEN 8192
#define H_N 8
#define D_DIM 64
#define NH (N_B * H_N)
#define EPS 1e-6f
#define ROWSTRIDE (H_N * D_DIM)   // 512 floats between consecutive s rows

typedef __attribute__((ext_vector_type(8)))  __bf16 bf16x8;
typedef __attribute__((ext_vector_type(4)))  float  f32x4;
typedef __attribute__((ext_vector_type(4)))  int    i32x4;

__device__ __forceinline__ float felu1(float x) {
    return x > 0.0f ? x + 1.0f : __expf(x);
}
__device__ __forceinline__ unsigned bfb(float f) {
    __bf16 h = (__bf16)f;                       // RNE convert
    return (unsigned)__builtin_bit_cast(unsigned short, h);
}
__device__ __forceinline__ int pack2bf(float a, float b) {
    return (int)(bfb(a) | (bfb(b) << 16));
}

// ---------------- Phase 1a: ONE-SHOT MFMA KV partial ------------------------
// out_kernel's proven execution shape: issue ALL global loads in one burst at
// block start -> convert -> ONE barrier -> pure-LDS MFMA -> store. Latency
// hiding comes from cross-block TLP (4096-block grid, R8 head-innermost remap),
// not intra-block pipelining. Staging = R10's verified column-gather
// (256 B/instr, FETCH-clean) + R10's verified XOR-octet LDS layout
// (0 bank conflicts; row-XOR key: (16w+(l&15))&7 == l&7).
// ROUNDS=1: 128 s-rows/block, nchunk=64 (needs ~69 MB ws).
// ROUNDS=2: fallback, 256 s-rows/block in 2 one-shot rounds, nchunk=32 (34 MB).
template<int ROUNDS>
__global__ __launch_bounds__(256) void kv_partial_kernel(
        const float* __restrict__ Kin, const float* __restrict__ Vin,
        float* __restrict__ kvp,   // [NH*nchunk][64*64]
        float* __restrict__ ksp) { // [NH*nchunk][64]
    constexpr int NCH  = 64 / ROUNDS;           // chunks per (n,h)
    constexpr int CLOG = (ROUNDS == 1) ? 6 : 5;
    __shared__ __align__(16) unsigned KT[64 * 64];  // 16 KB: row d, 64 dwords
    __shared__ __align__(16) unsigned VT[64 * 64];  // 16 KB: row m, 64 dwords

    const int b    = blockIdx.x;
    const int h_i  = b & 7;
    const int rest = b >> 3;
    const int c    = rest & (NCH - 1);
    const int n_i  = rest >> CLOG;
    const int ob   = (n_i * H_N + h_i) * NCH + c;
    const int s0   = c * (ROUNDS * 128);

    const int t = threadIdx.x;
    const int w = t >> 6;        // wave 0..3
    const int l = t & 63;        // lane = d (or m) column

    const float* Kb = Kin + (size_t)n_i * S_LEN * ROWSTRIDE + (size_t)h_i * D_DIM;
    const float* Vb = Vin + (size_t)n_i * S_LEN * ROWSTRIDE + (size_t)h_i * D_DIM;

    float kraw[32], vraw[32];    // one-shot burst: 32 s-rows of col l, K and V
    float ksum = 0.0f;

    auto issue = [&](int r) {
        const size_t base = (size_t)(s0 + r * 128 + 32 * w) * ROWSTRIDE + l;
        #pragma unroll
        for (int e = 0; e < 32; ++e) kraw[e] = Kb[base + (size_t)e * ROWSTRIDE];
        #pragma unroll
        for (int e = 0; e < 32; ++e) vraw[e] = Vb[base + (size_t)e * ROWSTRIDE];
    };

    // phi(K) + RNE bf16 s-pair packing + XOR-octet LDS write (R10 scheme).
    // Wave w holds s-pairs 16w..16w+15 -> sub = w>>1 (64-s half),
    // logical octets 4(w&1)+j, physical = logical ^ (l&7).
    auto convwrite = [&]() {
        int kp[16], vp[16];
        #pragma unroll
        for (int p = 0; p < 16; ++p) {
            const float a0 = felu1(kraw[2 * p]);
            const float a1 = felu1(kraw[2 * p + 1]);
            ksum += a0 + a1;
            kp[p] = pack2bf(a0, a1);
            vp[p] = pack2bf(vraw[2 * p], vraw[2 * p + 1]);
        }
        unsigned* kr = &KT[l * 64 + (w >> 1) * 32];
        unsigned* vr = &VT[l * 64 + (w >> 1) * 32];
        #pragma unroll
        for (int j = 0; j < 4; ++j) {
            const int po = ((4 * (w & 1) + j) ^ (l & 7)) * 4;
            *(i32x4*)&kr[po] = (i32x4){kp[4*j], kp[4*j+1], kp[4*j+2], kp[4*j+3]};
            *(i32x4*)&vr[po] = (i32x4){vp[4*j], vp[4*j+1], vp[4*j+2], vp[4*j+3]};
        }
    };

    f32x4 acc[4];
    #pragma unroll
    for (int i = 0; i < 4; ++i) acc[i] = (f32x4){0.f, 0.f, 0.f, 0.f};

    // compute: wave w owns output d-rows 16w..16w+15 (R10's verified frags)
    const int arow = 16 * w + (l & 15);
    auto compute = [&]() {
        #pragma unroll
        for (int sub = 0; sub < 2; ++sub) {
            #pragma unroll
            for (int ks = 0; ks < 2; ++ks) {
                const int g = ((4 * ks + (l >> 4)) ^ (l & 7)) * 4;
                const bf16x8 A = __builtin_bit_cast(bf16x8,
                    *(const i32x4*)&KT[arow * 64 + sub * 32 + g]);
                #pragma unroll
                for (int mt = 0; mt < 4; ++mt) {
                    const bf16x8 B = __builtin_bit_cast(bf16x8,
                        *(const i32x4*)&VT[(16 * mt + (l & 15)) * 64 + sub * 32 + g]);
                    acc[mt] = __builtin_amdgcn_mfma_f32_16x16x32_bf16(A, B, acc[mt], 0, 0, 0);
                }
            }
        }
    };

    issue(0);
    #pragma unroll
    for (int r = 0; r < ROUNDS; ++r) {
        convwrite();
        __syncthreads();            // LDS visible to all waves
        compute();
        if (r + 1 < ROUNDS) {
            issue(r + 1);           // next burst flies over the barrier
            __syncthreads();        // protect LDS reads before overwrite
        }
    }

    // ---- store partial KV: D col = l&15 (m), row = (l>>4)*4 + reg (d) ----
    float* kvo = kvp + (size_t)ob * (D_DIM * D_DIM);
    #pragma unroll
    for (int mt = 0; mt < 4; ++mt) {
        #pragma unroll
        for (int r = 0; r < 4; ++r) {
            const int row = 16 * w + (l >> 4) * 4 + r;   // d
            const int col = 16 * mt + (l & 15);          // m
            kvo[row * 64 + col] = acc[mt][r];
        }
    }

    // ---- ksum: per-thread (col, wave) partial -> LDS reduce ----
    __syncthreads();                // compute reads done; reuse KT
    float* ksl = (float*)&KT[0];
    ksl[w * 64 + l] = ksum;
    __syncthreads();
    if (t < D_DIM) {
        ksp[(size_t)ob * D_DIM + t] =
            ksl[t] + ksl[64 + t] + ksl[128 + t] + ksl[192 + t];
    }
}

// ---------------- Phase 1b: reduce partials -> final KV, Ksum ----------------
template<int NCH>
__global__ __launch_bounds__(256) void kv_reduce_kernel(
        const float* __restrict__ kvp, const float* __restrict__ ksp,
        float* __restrict__ KV, float* __restrict__ Ksum) {
    const int nh = blockIdx.x >> 4;
    const int eb = blockIdx.x & 15;
    const int t  = threadIdx.x;
    const int e  = eb * 256 + t;
    float s = 0.0f;
    const float* base = kvp + (size_t)nh * NCH * (D_DIM * D_DIM) + e;
    #pragma unroll 8
    for (int c = 0; c < NCH; ++c)
        s += base[(size_t)c * (D_DIM * D_DIM)];
    KV[(size_t)nh * (D_DIM * D_DIM) + e] = s;
    if (eb == 0 && t < D_DIM) {
        float ks = 0.0f;
        #pragma unroll 8
        for (int c = 0; c < NCH; ++c)
            ks += ksp[(size_t)nh * NCH * D_DIM + (size_t)c * D_DIM + t];
        Ksum[(size_t)nh * D_DIM + t] = ks;
    }
}

// ---------------- Phase 2: out = (Q·KV) / (Q·Ksum + eps) ----------------
// Grid remap: b = ((n*nblk + rb) * 8) + h (R8, kept -- ~6.4 TB/s measured).
__global__ __launch_bounds__(256) void out_kernel(
        const float* __restrict__ Qin, const float* __restrict__ KV,
        const float* __restrict__ Ksum, float* __restrict__ Out) {
    constexpr int RPB  = 128;
    constexpr int QPAD = 68;
    __shared__ __align__(16) float KVs[D_DIM][D_DIM];   // 16 KB
    __shared__ __align__(16) float Kss[D_DIM];
    __shared__ __align__(16) float Qs[RPB][QPAD];       // 34.8 KB, XOR-swizzled cols

    const int b    = blockIdx.x;
    const int nblk = S_LEN / RPB;          // 64
    const int h_i  = b & 7;
    const int rest = b >> 3;
    const int rb   = rest & (nblk - 1);
    const int n_i  = rest >> 6;            // nblk = 64
    const int nh   = n_i * H_N + h_i;
    const int t    = threadIdx.x;

    const float* Qb = Qin + (size_t)n_i * S_LEN * ROWSTRIDE + (size_t)h_i * D_DIM;
    float*       Ob = Out + (size_t)n_i * S_LEN * ROWSTRIDE + (size_t)h_i * D_DIM;

    {
        const float4* src = (const float4*)(KV + (size_t)nh * (D_DIM * D_DIM));
        float4* dst = (float4*)(&KVs[0][0]);
        #pragma unroll
        for (int i = 0; i < 4; ++i) dst[t + 256 * i] = src[t + 256 * i];
        if (t < 16) ((float4*)Kss)[t] = ((const float4*)(Ksum + (size_t)nh * D_DIM))[t];
    }

    const int ltx = t & 15, lty = t >> 4;
    const int sbase = rb * RPB;
    #pragma unroll
    for (int i = 0; i < 8; ++i) {
        const int row = lty + 16 * i;
        const float4 q = *(const float4*)(Qb + (size_t)(sbase + row) * ROWSTRIDE + ltx * 4);
        float4 f;
        f.x = felu1(q.x); f.y = felu1(q.y); f.z = felu1(q.z); f.w = felu1(q.w);
        const int pc = (ltx * 4) ^ (((row >> 2) & 7) << 2);
        *(float4*)&Qs[row][pc] = f;
    }
    __syncthreads();

    const int rg = t >> 3;                 // 0..31 -> rows rg*4..rg*4+3
    const int mg = t & 7;                  // 0..7  -> cols mg*8..mg*8+7
    const int r0 = rg * 4, m0 = mg * 8;
    const int sw = ((rg & 7) << 2);

    float acc[4][8];
    float zz[4];
    #pragma unroll
    for (int r = 0; r < 4; ++r) {
        zz[r] = 0.0f;
        #pragma unroll
        for (int m = 0; m < 8; ++m) acc[r][m] = 0.0f;
    }

    #pragma unroll
    for (int d0 = 0; d0 < D_DIM; d0 += 4) {
        const float4 ks4 = *(const float4*)&Kss[d0];
        float4 qr[4];
        #pragma unroll
        for (int r = 0; r < 4; ++r) {
            qr[r] = *(const float4*)&Qs[r0 + r][d0 ^ sw];
            zz[r] += qr[r].x * ks4.x + qr[r].y * ks4.y
                   + qr[r].z * ks4.z + qr[r].w * ks4.w;
        }
        #pragma unroll
        for (int j = 0; j < 4; ++j) {
            const float4 kva = *(const float4*)&KVs[d0 + j][m0];
            const float4 kvb = *(const float4*)&KVs[d0 + j][m0 + 4];
            #pragma unroll
            for (int r = 0; r < 4; ++r) {
                const float q = (&qr[r].x)[j];
                acc[r][0] += q * kva.x; acc[r][1] += q * kva.y;
                acc[r][2] += q * kva.z; acc[r][3] += q * kva.w;
                acc[r][4] += q * kvb.x; acc[r][5] += q * kvb.y;
                acc[r][6] += q * kvb.z; acc[r][7] += q * kvb.w;
            }
        }
    }

    #pragma unroll
    for (int r = 0; r < 4; ++r) {
        const float z = 1.0f / (zz[r] + EPS);
        float4 o1, o2;
        o1.x = acc[r][0] * z; o1.y = acc[r][1] * z;
        o1.z = acc[r][2] * z; o1.w = acc[r][3] * z;
        o2.x = acc[r][4] * z; o2.y = acc[r][5] * z;
        o2.z = acc[r][6] * z; o2.w = acc[r][7] * z;
        float* op = Ob + (size_t)(sbase + r0 + r) * ROWSTRIDE + m0;
        *(float4*)op       = o1;
        *(float4*)(op + 4) = o2;
    }
}

extern "C" void kernel_launch(void* const* d_in, const int* in_sizes, int n_in,
                              void* d_out, int out_size, void* d_ws, size_t ws_size,
                              hipStream_t stream) {
    const float* q = (const float*)d_in[0];
    const float* k = (const float*)d_in[1];
    const float* v = (const float*)d_in[2];
    float* out = (float*)d_out;

    const size_t need64 = ((size_t)NH * 64 * (4096 + 64)
                         + (size_t)NH * (4096 + 64)) * sizeof(float); // ~69 MB

    if (ws_size >= need64) {
        const int nch = 64;
        float* kvp  = (float*)d_ws;
        float* ksp  = kvp + (size_t)NH * nch * D_DIM * D_DIM;
        float* KVf  = ksp + (size_t)NH * nch * D_DIM;
        float* Ksum = KVf + (size_t)NH * D_DIM * D_DIM;
        kv_partial_kernel<1><<<N_B * nch * H_N, 256, 0, stream>>>(k, v, kvp, ksp);
        kv_reduce_kernel<64><<<NH * 16, 256, 0, stream>>>(kvp, ksp, KVf, Ksum);
        out_kernel<<<NH * (S_LEN / 128), 256, 0, stream>>>(q, KVf, Ksum, out);
    } else {
        const int nch = 32;
        float* kvp  = (float*)d_ws;
        float* ksp  = kvp + (size_t)NH * nch * D_DIM * D_DIM;
        float* KVf  = ksp + (size_t)NH * nch * D_DIM;
        float* Ksum = KVf + (size_t)NH * D_DIM * D_DIM;
        kv_partial_kernel<2><<<N_B * nch * H_N, 256, 0, stream>>>(k, v, kvp, ksp);
        kv_reduce_kernel<32><<<NH * 16, 256, 0, stream>>>(kvp, ksp, KVf, Ksum);
        out_kernel<<<NH * (S_LEN / 128), 256, 0, stream>>>(q, KVf, Ksum, out);
    }
}